// Round 6
// baseline (2346.079 us; speedup 1.0000x reference)
//
#include <hip/hip_runtime.h>

#define NN 50000
#define NE 400000
#define DD 128
#define HH 4
#define DHH 32
#define TT 3
#define RR 6
#define LL 2
#define EPSF 1e-5f

typedef unsigned short ushort_t;
typedef unsigned int uint_t;

__device__ inline ushort_t f2bf(float f){
  union { float f; uint_t u; } x; x.f = f;
  uint_t r = x.u + 0x7fffu + ((x.u >> 16) & 1u);
  return (ushort_t)(r >> 16);
}
__device__ inline float bf2f(ushort_t u){
  union { uint_t u; float f; } x; x.u = ((uint_t)u) << 16;
  return x.f;
}

// ---------------- CSR build ----------------
__global__ void hist_kernel(const int* __restrict__ dst, int* __restrict__ cnt){
  int e = blockIdx.x*256 + threadIdx.x;
  if (e < NE) atomicAdd(&cnt[dst[e]], 1);
}

__global__ void scan_kernel(const int* __restrict__ deg, int* __restrict__ rowptr){
  __shared__ int wsum[16];
  __shared__ int carrySh;
  int tid = threadIdx.x, lane = tid & 63, w = tid >> 6;
  if (tid == 0){ carrySh = 0; rowptr[0] = 0; }
  __syncthreads();
  for (int base = 0; base < NN; base += 1024){
    int i = base + tid;
    int v = (i < NN) ? deg[i] : 0;
    int s = v;
    #pragma unroll
    for (int off=1; off<64; off<<=1){ int t = __shfl_up(s, off); if (lane >= off) s += t; }
    if (lane == 63) wsum[w] = s;
    __syncthreads();
    if (w == 0 && lane < 16){
      int t = wsum[lane];
      #pragma unroll
      for (int off=1; off<16; off<<=1){ int u = __shfl_up(t, off); if (lane >= off) t += u; }
      wsum[lane] = t;
    }
    __syncthreads();
    int waveOff = (w == 0) ? 0 : wsum[w-1];
    int incl = s + waveOff + carrySh;
    if (i < NN) rowptr[i+1] = incl;
    __syncthreads();
    if (tid == 0) carrySh += wsum[15];
    __syncthreads();
  }
}

// scatter: packed (src | etype<<27) in CSR order
__global__ void scatter_kernel(const int* __restrict__ dst, const int* __restrict__ src,
                               const int* __restrict__ etype, const int* __restrict__ rowptr,
                               int* __restrict__ cnt, uint_t* __restrict__ sr){
  int e = blockIdx.x*256 + threadIdx.x;
  if (e < NE){
    int d = dst[e];
    int pos = rowptr[d] + atomicAdd(&cnt[d], 1);
    sr[pos] = (uint_t)src[e] | ((uint_t)etype[e] << 27);
  }
}

// ---------------- typed K/Q/V GEMM (K,V packed bf16 pair; Q fp32) ----------------
__global__ __launch_bounds__(256) void kqv_kernel(
    const float* __restrict__ x, const int* __restrict__ ntype,
    const float* __restrict__ Wk, const float* __restrict__ Wq, const float* __restrict__ Wv,
    uint_t* __restrict__ kvout, float* __restrict__ qout)
{
  __shared__ float xs[16][DD];
  __shared__ int nts[16];
  int tid = threadIdx.x;
  int n0 = blockIdx.x * 16;
  #pragma unroll
  for (int it=0; it<8; it++){
    int i = tid + it*256;
    xs[i>>7][i&127] = x[(size_t)n0*DD + i];
  }
  if (tid < 16) nts[tid] = ntype[n0 + tid];
  __syncthreads();
  int c = tid & 127, nb = (tid >> 7) * 8;
  float ak[8], aq[8], av[8];
  #pragma unroll
  for (int j=0;j<8;j++){ ak[j]=0.f; aq[j]=0.f; av[j]=0.f; }
  int t0 = nts[nb];
  bool uni = true;
  #pragma unroll
  for (int j=1;j<8;j++) uni = uni && (nts[nb+j] == t0);
  if (uni){
    const float* wk = Wk + (size_t)t0*DD*DD + c;
    const float* wq = Wq + (size_t)t0*DD*DD + c;
    const float* wv = Wv + (size_t)t0*DD*DD + c;
    for (int d=0; d<DD; d+=4){
      float k0=wk[(d+0)*DD], k1=wk[(d+1)*DD], k2=wk[(d+2)*DD], k3=wk[(d+3)*DD];
      float q0=wq[(d+0)*DD], q1=wq[(d+1)*DD], q2=wq[(d+2)*DD], q3=wq[(d+3)*DD];
      float v0=wv[(d+0)*DD], v1=wv[(d+1)*DD], v2=wv[(d+2)*DD], v3=wv[(d+3)*DD];
      #pragma unroll
      for (int j=0;j<8;j++){
        float4 xv = *(const float4*)&xs[nb+j][d];
        ak[j] += xv.x*k0 + xv.y*k1 + xv.z*k2 + xv.w*k3;
        aq[j] += xv.x*q0 + xv.y*q1 + xv.z*q2 + xv.w*q3;
        av[j] += xv.x*v0 + xv.y*v1 + xv.z*v2 + xv.w*v3;
      }
    }
  } else {
    #pragma unroll
    for (int j=0;j<8;j++){
      int t = nts[nb+j];
      const float* wk = Wk + (size_t)t*DD*DD + c;
      const float* wq = Wq + (size_t)t*DD*DD + c;
      const float* wv = Wv + (size_t)t*DD*DD + c;
      float sk=0.f, sq=0.f, sv=0.f;
      for (int d=0; d<DD; d+=4){
        float4 xv = *(const float4*)&xs[nb+j][d];
        sk += xv.x*wk[d*DD] + xv.y*wk[(d+1)*DD] + xv.z*wk[(d+2)*DD] + xv.w*wk[(d+3)*DD];
        sq += xv.x*wq[d*DD] + xv.y*wq[(d+1)*DD] + xv.z*wq[(d+2)*DD] + xv.w*wq[(d+3)*DD];
        sv += xv.x*wv[d*DD] + xv.y*wv[(d+1)*DD] + xv.z*wv[(d+2)*DD] + xv.w*wv[(d+3)*DD];
      }
      ak[j]=sk; aq[j]=sq; av[j]=sv;
    }
  }
  #pragma unroll
  for (int j=0;j<8;j++){
    size_t row = (size_t)(n0 + nb + j)*DD + c;
    kvout[row] = (uint_t)f2bf(ak[j]) | ((uint_t)f2bf(av[j]) << 16);
    qout[row]  = aq[j];
  }
}

// ---------------- fused edge pipeline (16-node blocks, LDS qhat) ----------------
// 256 threads = 2 groups x 128; qhat for 16 nodes x 6 relations computed once
// into LDS (bf16); each group runs 8 nodes' batched online-softmax edge loops.
__global__ __launch_bounds__(256) void edge_kernel(
    const uint_t* __restrict__ kvb, const float* __restrict__ qb,
    const int* __restrict__ rowptr, const uint_t* __restrict__ src_r,
    const float* __restrict__ Watt, const float* __restrict__ pri,
    ushort_t* __restrict__ sacc)
{
  __shared__ float qs[16][DD];
  __shared__ ushort_t qh[16][RR][DD];
  __shared__ float psh[HH*RR];
  int tid = threadIdx.x;
  int n0 = blockIdx.x * 16;
  #pragma unroll
  for (int it=0; it<8; it++){
    int i = tid + it*256;
    qs[i>>7][i&127] = qb[(size_t)n0*DD + i];
  }
  if (tid < HH*RR) psh[tid] = pri[tid] * 0.17677669529663687f;
  __syncthreads();
  int c = tid & 127;
  int h = c >> 5, dd = c & 31;
  int g = tid >> 7;                 // node-group 0/1
  // qhat[j][r][c] = sum_o Watt[h][r][dd][o] * q[j][h*32+o]
  #pragma unroll
  for (int r=0;r<RR;r++){
    const float4* w4 = (const float4*)(Watt + (((h*RR + r) << 10) + (dd << 5)));
    float4 w[8];
    #pragma unroll
    for (int i4=0;i4<8;i4++) w[i4] = w4[i4];
    #pragma unroll
    for (int jj=0;jj<8;jj++){
      int j = g*8 + jj;
      const float4* q4 = (const float4*)&qs[j][h<<5];
      float s = 0.f;
      #pragma unroll
      for (int i4=0;i4<8;i4++){
        float4 qv = q4[i4];
        s += w[i4].x*qv.x + w[i4].y*qv.y + w[i4].z*qv.z + w[i4].w*qv.w;
      }
      qh[j][r][c] = f2bf(s);
    }
  }
  __syncthreads();

  for (int jn=0; jn<8; jn++){
    int jl = g*8 + jn;
    int n = n0 + jl;
    int b = rowptr[n], e1 = rowptr[n+1];
    float a0=0.f,a1=0.f,a2=0.f,a3=0.f,a4=0.f,a5=0.f;
    float den = 0.f, m = -1e30f;
    for (int i=b; i<e1; i+=8){
      int m8 = e1 - i; if (m8 > 8) m8 = 8;
      uint_t sr[8];
      #pragma unroll
      for (int jj=0;jj<8;jj++) sr[jj] = src_r[i + ((jj < m8) ? jj : (m8-1))];
      uint_t kv[8];
      #pragma unroll
      for (int jj=0;jj<8;jj++)
        kv[jj] = kvb[(size_t)(sr[jj] & 0x07FFFFFFu)*DD + c];
      float aa[8];
      #pragma unroll
      for (int jj=0;jj<8;jj++){
        int r = (int)(sr[jj] >> 27);
        float kf = bf2f((ushort_t)(kv[jj] & 0xffffu));
        float p = kf * bf2f(qh[jl][r][c]);
        #pragma unroll
        for (int off=16; off>0; off>>=1) p += __shfl_xor(p, off);
        aa[jj] = (jj < m8) ? p * psh[h*RR + r] : -1e30f;
      }
      float mb = aa[0];
      #pragma unroll
      for (int jj=1;jj<8;jj++) mb = fmaxf(mb, aa[jj]);
      float mnew = fmaxf(m, mb);
      float corr = __expf(m - mnew);
      m = mnew;
      den *= corr; a0*=corr; a1*=corr; a2*=corr; a3*=corr; a4*=corr; a5*=corr;
      #pragma unroll
      for (int jj=0;jj<8;jj++){
        float ex = __expf(aa[jj] - mnew);
        den += ex;
        float vf = bf2f((ushort_t)(kv[jj] >> 16));
        float exv = ex * vf;
        int r = (int)(sr[jj] >> 27);
        a0 += (r==0)? exv : 0.f;
        a1 += (r==1)? exv : 0.f;
        a2 += (r==2)? exv : 0.f;
        a3 += (r==3)? exv : 0.f;
        a4 += (r==4)? exv : 0.f;
        a5 += (r==5)? exv : 0.f;
      }
    }
    float inv = (den > 0.f) ? 1.f/den : 0.f;
    ushort_t* sb = sacc + (size_t)n*(RR*DD);
    sb[(0<<7)+c] = f2bf(a0*inv);
    sb[(1<<7)+c] = f2bf(a1*inv);
    sb[(2<<7)+c] = f2bf(a2*inv);
    sb[(3<<7)+c] = f2bf(a3*inv);
    sb[(4<<7)+c] = f2bf(a4*inv);
    sb[(5<<7)+c] = f2bf(a5*inv);
  }
}

// ---------------- W_msg apply + typed Wa GEMM + skip gate + LayerNorm ----------------
__global__ __launch_bounds__(256) void ha_kernel(
    const ushort_t* __restrict__ sacc, const float* __restrict__ x, const int* __restrict__ ntype,
    const float* __restrict__ Wmsg, const float* __restrict__ Wa, const float* __restrict__ skipl,
    const float* __restrict__ lng, const float* __restrict__ lnb,
    float* __restrict__ xout)
{
  __shared__ ushort_t ss[16*RR*DD];   // 16 nodes x 768 = 24KB
  __shared__ float xs[16][DD];
  __shared__ int nts[16];
  int tid = threadIdx.x;
  int n0 = blockIdx.x * 16;
  // stage sacc tile (node stride = 768 ushorts)
  #pragma unroll
  for (int it=0; it<12; it++){
    int c4 = tid + it*256;            // 3072 chunks of 4 ushorts
    int j = c4 / 192;
    int k = (c4 - j*192) * 4;
    *(uint2*)&ss[j*768 + k] = *(const uint2*)&sacc[(size_t)(n0+j)*768 + k];
  }
  if (tid < 16) nts[tid] = ntype[n0 + tid];
  __syncthreads();
  int c = tid & 127, nb = (tid >> 7) * 8;
  int h = c >> 5, o = c & 31;
  // msg stage: agg[n][c] = sum_r sum_d Wmsg[h][r][d][o] * sacc[n][r][h*32+d]
  float agg8[8];
  #pragma unroll
  for (int j=0;j<8;j++) agg8[j]=0.f;
  #pragma unroll
  for (int r=0;r<RR;r++){
    const float* wm = Wmsg + ((h*RR + r) << 10) + o;
    const ushort_t* s0 = ss + r*DD + (h<<5);
    #pragma unroll 8
    for (int d=0; d<DHH; d++){
      float w = wm[d << 5];
      #pragma unroll
      for (int j=0;j<8;j++)
        agg8[j] += w * bf2f(s0[(nb+j)*768 + d]);
    }
  }
  #pragma unroll
  for (int j=0;j<8;j++) xs[nb+j][c] = agg8[j];
  __syncthreads();
  // typed Wa GEMM
  float acc[8];
  #pragma unroll
  for (int j=0;j<8;j++) acc[j]=0.f;
  int t0 = nts[nb];
  bool uni = true;
  #pragma unroll
  for (int j=1;j<8;j++) uni = uni && (nts[nb+j] == t0);
  if (uni){
    const float* wa = Wa + (size_t)t0*DD*DD + c;
    for (int d=0; d<DD; d+=4){
      float w0=wa[(d+0)*DD], w1=wa[(d+1)*DD], w2=wa[(d+2)*DD], w3=wa[(d+3)*DD];
      #pragma unroll
      for (int j=0;j<8;j++){
        float4 xv = *(const float4*)&xs[nb+j][d];
        acc[j] += xv.x*w0 + xv.y*w1 + xv.z*w2 + xv.w*w3;
      }
    }
  } else {
    #pragma unroll
    for (int j=0;j<8;j++){
      int t = nts[nb+j];
      const float* wa = Wa + (size_t)t*DD*DD + c;
      float sacc2 = 0.f;
      for (int d=0; d<DD; d+=4){
        float4 xv = *(const float4*)&xs[nb+j][d];
        sacc2 += xv.x*wa[d*DD] + xv.y*wa[(d+1)*DD] + xv.z*wa[(d+2)*DD] + xv.w*wa[(d+3)*DD];
      }
      acc[j] = sacc2;
    }
  }
  __syncthreads();
  // skip gate; store x + ho into xs for LN
  #pragma unroll
  for (int j=0;j<8;j++){
    int n = n0 + nb + j;
    float sk = 1.f/(1.f + __expf(-skipl[nts[nb+j]]));
    float xv = x[(size_t)n*DD + c];
    xs[nb+j][c] = acc[j]*sk + xv*(2.f - sk);   // x + (acc*sk + x*(1-sk))
  }
  __syncthreads();
  // fused LayerNorm: 4 wave-groups of 64 lanes, each does 4 rows
  int lane = tid & 63;
  int r0 = tid >> 6;
  #pragma unroll
  for (int rr = r0; rr < 16; rr += 4){
    float t0v = xs[rr][lane], t1v = xs[rr][lane+64];
    float s = t0v + t1v;
    #pragma unroll
    for (int off=32; off>0; off>>=1) s += __shfl_xor(s, off);
    float mu = s * (1.f/DD);
    float d0 = t0v-mu, d1 = t1v-mu;
    float vs = d0*d0 + d1*d1;
    #pragma unroll
    for (int off=32; off>0; off>>=1) vs += __shfl_xor(vs, off);
    float inv = rsqrtf(vs*(1.f/DD) + EPSF);
    size_t base = (size_t)(n0+rr)*DD;
    xout[base+lane]    = d0*inv*lng[lane]    + lnb[lane];
    xout[base+lane+64] = d1*inv*lng[lane+64] + lnb[lane+64];
  }
}

// ---------------- final mix + LayerNorm ----------------
__global__ __launch_bounds__(256) void final_kernel(
    const float* __restrict__ x1, const float* __restrict__ x2,
    const float* __restrict__ aggw, const float* __restrict__ g, const float* __restrict__ b,
    float* __restrict__ out)
{
  int lane = threadIdx.x & 63;
  int n = blockIdx.x*4 + (threadIdx.x >> 6);
  float a0 = aggw[0], a1 = aggw[1];
  float m = fmaxf(a0, a1);
  float e0 = __expf(a0-m), e1 = __expf(a1-m);
  float inv01 = 1.f/(e0+e1);
  float w0 = e0*inv01, w1 = e1*inv01;
  size_t base = (size_t)n*DD;
  float t0 = w0*x1[base+lane]    + w1*x2[base+lane];
  float t1 = w0*x1[base+lane+64] + w1*x2[base+lane+64];
  float s = t0 + t1;
  #pragma unroll
  for (int off=32; off>0; off>>=1) s += __shfl_xor(s, off);
  float mu = s * (1.f/DD);
  float d0 = t0-mu, d1 = t1-mu;
  float vs = d0*d0 + d1*d1;
  #pragma unroll
  for (int off=32; off>0; off>>=1) vs += __shfl_xor(vs, off);
  float invv = rsqrtf(vs*(1.f/DD) + EPSF);
  out[base+lane]    = d0*invv*g[lane]    + b[lane];
  out[base+lane+64] = d1*invv*g[lane+64] + b[lane+64];
}

extern "C" void kernel_launch(void* const* d_in, const int* in_sizes, int n_in,
                              void* d_out, int out_size, void* d_ws, size_t ws_size,
                              hipStream_t stream)
{
  (void)in_sizes; (void)n_in; (void)out_size; (void)ws_size;
  const float* h_in  = (const float*)d_in[0];
  const int*   src   = (const int*)d_in[1];
  const int*   dst   = (const int*)d_in[2];
  const int*   ntype = (const int*)d_in[3];
  const int*   etype = (const int*)d_in[4];
  const float* Wk    = (const float*)d_in[5];
  const float* Wq    = (const float*)d_in[6];
  const float* Wv    = (const float*)d_in[7];
  const float* Wa    = (const float*)d_in[8];
  const float* Watt  = (const float*)d_in[9];
  const float* Wmsg  = (const float*)d_in[10];
  const float* pri   = (const float*)d_in[11];
  const float* skp   = (const float*)d_in[12];
  const float* lng   = (const float*)d_in[13];
  const float* lnb   = (const float*)d_in[14];
  const float* aggw  = (const float*)d_in[15];
  const float* aggg  = (const float*)d_in[16];
  const float* aggb_ = (const float*)d_in[17];

  size_t P = (size_t)NN*DD;
  uint_t* kvbuf = (uint_t*)d_ws;                   // P packed (k,v) bf16
  float* qbuf  = (float*)(kvbuf + P);              // P f32
  ushort_t* sacc = (ushort_t*)(qbuf + P);          // N*R*D bf16
  float* out0  = (float*)(sacc + (size_t)NN*RR*DD);// P f32 (layer-0 output)
  int* rowptr = (int*)(out0 + P);
  int* cnt    = rowptr + NN + 1;
  uint_t* srcr = (uint_t*)(cnt + NN);              // NE packed (src | etype<<27)
  float* xout = (float*)d_out;

  // CSR by dst
  hipMemsetAsync(cnt, 0, NN*sizeof(int), stream);
  hist_kernel<<<(NE+255)/256, 256, 0, stream>>>(dst, cnt);
  scan_kernel<<<1, 1024, 0, stream>>>(cnt, rowptr);
  hipMemsetAsync(cnt, 0, NN*sizeof(int), stream);
  scatter_kernel<<<(NE+255)/256, 256, 0, stream>>>(dst, src, etype, rowptr, cnt, srcr);

  const float* x = h_in;
  for (int l=0; l<LL; l++){
    const float* Wk_l  = Wk  + (size_t)l*TT*DD*DD;
    const float* Wq_l  = Wq  + (size_t)l*TT*DD*DD;
    const float* Wv_l  = Wv  + (size_t)l*TT*DD*DD;
    const float* Wa_l  = Wa  + (size_t)l*TT*DD*DD;
    const float* Wat_l = Watt + (size_t)l*HH*RR*DHH*DHH;
    const float* Wms_l = Wmsg + (size_t)l*HH*RR*DHH*DHH;
    const float* pri_l = pri + (size_t)l*HH*RR;
    const float* skp_l = skp + (size_t)l*TT;

    kqv_kernel<<<NN/16, 256, 0, stream>>>(x, ntype, Wk_l, Wq_l, Wv_l, kvbuf, qbuf);
    edge_kernel<<<NN/16, 256, 0, stream>>>(kvbuf, qbuf, rowptr, srcr, Wat_l, pri_l, sacc);
    float* xo = (l == 0) ? out0 : xout;
    ha_kernel<<<NN/16, 256, 0, stream>>>(sacc, x, ntype, Wms_l, Wa_l, skp_l,
                                         lng + (size_t)l*DD, lnb + (size_t)l*DD, xo);
    x = xo;
  }
  final_kernel<<<NN/4, 256, 0, stream>>>(out0, xout, aggw, aggg, aggb_, xout);
}

// Round 7
// 990.800 us; speedup vs baseline: 2.3679x; 2.3679x over previous
//
#include <hip/hip_runtime.h>

#define NN 50000
#define NE 400000
#define DD 128
#define HH 4
#define DHH 32
#define TT 3
#define RR 6
#define LL 2
#define EPSF 1e-5f

typedef unsigned short ushort_t;
typedef unsigned int uint_t;

__device__ inline ushort_t f2bf(float f){
  union { float f; uint_t u; } x; x.f = f;
  uint_t r = x.u + 0x7fffu + ((x.u >> 16) & 1u);
  return (ushort_t)(r >> 16);
}
__device__ inline float bf2f(ushort_t u){
  union { uint_t u; float f; } x; x.u = ((uint_t)u) << 16;
  return x.f;
}

// ---------------- CSR build ----------------
__global__ void hist_kernel(const int* __restrict__ dst, int* __restrict__ cnt){
  int e = blockIdx.x*256 + threadIdx.x;
  if (e < NE) atomicAdd(&cnt[dst[e]], 1);
}

__global__ void scan_kernel(const int* __restrict__ deg, int* __restrict__ rowptr){
  __shared__ int wsum[16];
  __shared__ int carrySh;
  int tid = threadIdx.x, lane = tid & 63, w = tid >> 6;
  if (tid == 0){ carrySh = 0; rowptr[0] = 0; }
  __syncthreads();
  for (int base = 0; base < NN; base += 1024){
    int i = base + tid;
    int v = (i < NN) ? deg[i] : 0;
    int s = v;
    #pragma unroll
    for (int off=1; off<64; off<<=1){ int t = __shfl_up(s, off); if (lane >= off) s += t; }
    if (lane == 63) wsum[w] = s;
    __syncthreads();
    if (w == 0 && lane < 16){
      int t = wsum[lane];
      #pragma unroll
      for (int off=1; off<16; off<<=1){ int u = __shfl_up(t, off); if (lane >= off) t += u; }
      wsum[lane] = t;
    }
    __syncthreads();
    int waveOff = (w == 0) ? 0 : wsum[w-1];
    int incl = s + waveOff + carrySh;
    if (i < NN) rowptr[i+1] = incl;
    __syncthreads();
    if (tid == 0) carrySh += wsum[15];
    __syncthreads();
  }
}

// scatter: packed (src | etype<<27) and dst, both in CSR order
__global__ void scatter_kernel(const int* __restrict__ dst, const int* __restrict__ src,
                               const int* __restrict__ etype, const int* __restrict__ rowptr,
                               int* __restrict__ cnt, uint_t* __restrict__ sr, int* __restrict__ dp){
  int e = blockIdx.x*256 + threadIdx.x;
  if (e < NE){
    int d = dst[e];
    int pos = rowptr[d] + atomicAdd(&cnt[d], 1);
    sr[pos] = (uint_t)src[e] | ((uint_t)etype[e] << 27);
    dp[pos] = d;
  }
}

// ---------------- typed K/Q/V GEMM (K,V bf16; Q fp32) ----------------
__global__ __launch_bounds__(256) void kqv_kernel(
    const float* __restrict__ x, const int* __restrict__ ntype,
    const float* __restrict__ Wk, const float* __restrict__ Wq, const float* __restrict__ Wv,
    ushort_t* __restrict__ kout, float* __restrict__ qout, ushort_t* __restrict__ vout)
{
  __shared__ float xs[16][DD];
  __shared__ int nts[16];
  int tid = threadIdx.x;
  int n0 = blockIdx.x * 16;
  #pragma unroll
  for (int it=0; it<8; it++){
    int i = tid + it*256;
    xs[i>>7][i&127] = x[(size_t)n0*DD + i];
  }
  if (tid < 16) nts[tid] = ntype[n0 + tid];
  __syncthreads();
  int c = tid & 127, nb = (tid >> 7) * 8;
  float ak[8], aq[8], av[8];
  #pragma unroll
  for (int j=0;j<8;j++){ ak[j]=0.f; aq[j]=0.f; av[j]=0.f; }
  int t0 = nts[nb];
  bool uni = true;
  #pragma unroll
  for (int j=1;j<8;j++) uni = uni && (nts[nb+j] == t0);
  if (uni){
    const float* wk = Wk + (size_t)t0*DD*DD + c;
    const float* wq = Wq + (size_t)t0*DD*DD + c;
    const float* wv = Wv + (size_t)t0*DD*DD + c;
    for (int d=0; d<DD; d+=4){
      float k0=wk[(d+0)*DD], k1=wk[(d+1)*DD], k2=wk[(d+2)*DD], k3=wk[(d+3)*DD];
      float q0=wq[(d+0)*DD], q1=wq[(d+1)*DD], q2=wq[(d+2)*DD], q3=wq[(d+3)*DD];
      float v0=wv[(d+0)*DD], v1=wv[(d+1)*DD], v2=wv[(d+2)*DD], v3=wv[(d+3)*DD];
      #pragma unroll
      for (int j=0;j<8;j++){
        float4 xv = *(const float4*)&xs[nb+j][d];
        ak[j] += xv.x*k0 + xv.y*k1 + xv.z*k2 + xv.w*k3;
        aq[j] += xv.x*q0 + xv.y*q1 + xv.z*q2 + xv.w*q3;
        av[j] += xv.x*v0 + xv.y*v1 + xv.z*v2 + xv.w*v3;
      }
    }
  } else {
    #pragma unroll
    for (int j=0;j<8;j++){
      int t = nts[nb+j];
      const float* wk = Wk + (size_t)t*DD*DD + c;
      const float* wq = Wq + (size_t)t*DD*DD + c;
      const float* wv = Wv + (size_t)t*DD*DD + c;
      float sk=0.f, sq=0.f, sv=0.f;
      for (int d=0; d<DD; d+=4){
        float4 xv = *(const float4*)&xs[nb+j][d];
        sk += xv.x*wk[d*DD] + xv.y*wk[(d+1)*DD] + xv.z*wk[(d+2)*DD] + xv.w*wk[(d+3)*DD];
        sq += xv.x*wq[d*DD] + xv.y*wq[(d+1)*DD] + xv.z*wq[(d+2)*DD] + xv.w*wq[(d+3)*DD];
        sv += xv.x*wv[d*DD] + xv.y*wv[(d+1)*DD] + xv.z*wv[(d+2)*DD] + xv.w*wv[(d+3)*DD];
      }
      ak[j]=sk; aq[j]=sq; av[j]=sv;
    }
  }
  #pragma unroll
  for (int j=0;j<8;j++){
    size_t row = (size_t)(n0 + nb + j)*DD + c;
    kout[row]=f2bf(ak[j]); qout[row]=aq[j]; vout[row]=f2bf(av[j]);
  }
}

// ---------------- qhat: per-node, all relations, bf16 out ----------------
// qhat[n][r][h*32+dd] = sum_o Watt[h][r][dd][o] * q[n][h*32+o]
__global__ __launch_bounds__(256) void qhat_kernel(
    const float* __restrict__ qb, const float* __restrict__ Watt,
    ushort_t* __restrict__ qh)
{
  __shared__ float qs[16][DD];
  int tid = threadIdx.x;
  int n0 = blockIdx.x * 16;
  #pragma unroll
  for (int it=0; it<8; it++){
    int i = tid + it*256;
    qs[i>>7][i&127] = qb[(size_t)n0*DD + i];
  }
  __syncthreads();
  int c = tid & 127, g = tid >> 7;
  int h = c >> 5, dd = c & 31;
  for (int r=0;r<RR;r++){
    const float4* w4 = (const float4*)(Watt + (((h*RR + r) << 10) + (dd << 5)));
    float4 w0=w4[0], w1=w4[1], w2=w4[2], w3=w4[3], w4v=w4[4], w5=w4[5], w6=w4[6], w7=w4[7];
    #pragma unroll
    for (int jj=0;jj<8;jj++){
      int j = g*8 + jj;
      const float4* q4 = (const float4*)&qs[j][h<<5];
      float s = 0.f;
      float4 qv;
      qv=q4[0]; s += w0.x*qv.x + w0.y*qv.y + w0.z*qv.z + w0.w*qv.w;
      qv=q4[1]; s += w1.x*qv.x + w1.y*qv.y + w1.z*qv.z + w1.w*qv.w;
      qv=q4[2]; s += w2.x*qv.x + w2.y*qv.y + w2.z*qv.z + w2.w*qv.w;
      qv=q4[3]; s += w3.x*qv.x + w3.y*qv.y + w3.z*qv.z + w3.w*qv.w;
      qv=q4[4]; s += w4v.x*qv.x + w4v.y*qv.y + w4v.z*qv.z + w4v.w*qv.w;
      qv=q4[5]; s += w5.x*qv.x + w5.y*qv.y + w5.z*qv.z + w5.w*qv.w;
      qv=q4[6]; s += w6.x*qv.x + w6.y*qv.y + w6.z*qv.z + w6.w*qv.w;
      qv=q4[7]; s += w7.x*qv.x + w7.y*qv.y + w7.z*qv.z + w7.w*qv.w;
      qh[((size_t)(n0+j)*RR + r)*DD + c] = f2bf(s);
    }
  }
}

// ---------------- edge-parallel logits ----------------
// thread = (csr position p, head h); CSR order => consecutive threads share dst (qhat L1-hot)
__global__ __launch_bounds__(256) void logit_kernel(
    const ushort_t* __restrict__ kb, const ushort_t* __restrict__ qh,
    const uint_t* __restrict__ src_r, const int* __restrict__ dstp,
    const float* __restrict__ pri, float* __restrict__ aout)
{
  int idx = blockIdx.x*256 + threadIdx.x;
  int p = idx >> 2;
  if (p >= NE) return;
  int h = idx & 3;
  uint_t sr = src_r[p];
  int s = (int)(sr & 0x07FFFFFFu);
  int r = (int)(sr >> 27);
  int dn = dstp[p];
  const uint_t* kr = (const uint_t*)(kb + (size_t)s*DD + (h<<5));      // 32 bf16 = 16 words
  const uint_t* qr = (const uint_t*)(qh + ((size_t)dn*RR + r)*DD + (h<<5));
  float a = 0.f;
  #pragma unroll
  for (int i4=0; i4<4; i4++){
    uint4 kw = ((const uint4*)kr)[i4];
    uint4 qw = ((const uint4*)qr)[i4];
    a += bf2f((ushort_t)(kw.x&0xffffu))*bf2f((ushort_t)(qw.x&0xffffu))
       + bf2f((ushort_t)(kw.x>>16))   *bf2f((ushort_t)(qw.x>>16))
       + bf2f((ushort_t)(kw.y&0xffffu))*bf2f((ushort_t)(qw.y&0xffffu))
       + bf2f((ushort_t)(kw.y>>16))   *bf2f((ushort_t)(qw.y>>16))
       + bf2f((ushort_t)(kw.z&0xffffu))*bf2f((ushort_t)(qw.z&0xffffu))
       + bf2f((ushort_t)(kw.z>>16))   *bf2f((ushort_t)(qw.z>>16))
       + bf2f((ushort_t)(kw.w&0xffffu))*bf2f((ushort_t)(qw.w&0xffffu))
       + bf2f((ushort_t)(kw.w>>16))   *bf2f((ushort_t)(qw.w>>16));
  }
  aout[(size_t)p*HH + h] = a * pri[h*RR + r] * 0.17677669529663687f;
}

// ---------------- node-parallel softmax + v-reduce (wave per node) ----------------
// lane owns dims {2*lane, 2*lane+1}; head = lane>>4; no shfl, no barriers.
__global__ __launch_bounds__(256) void reduce_kernel(
    const ushort_t* __restrict__ vb, const float* __restrict__ aout,
    const int* __restrict__ rowptr, const uint_t* __restrict__ src_r,
    ushort_t* __restrict__ sacc)
{
  int n = blockIdx.x*4 + (threadIdx.x >> 6);
  if (n >= NN) return;
  int lane = threadIdx.x & 63;
  int h = lane >> 4;
  int b = rowptr[n], e1 = rowptr[n+1];
  float m = -1e30f;
  for (int i=b;i<e1;i++) m = fmaxf(m, aout[(size_t)i*HH + h]);
  float den = 0.f;
  for (int i=b;i<e1;i++) den += __expf(aout[(size_t)i*HH + h] - m);
  float a00=0.f,a01=0.f,a10=0.f,a11=0.f,a20=0.f,a21=0.f;
  float a30=0.f,a31=0.f,a40=0.f,a41=0.f,a50=0.f,a51=0.f;
  for (int i=b;i<e1;i++){
    uint_t sr = src_r[i];
    int s = (int)(sr & 0x07FFFFFFu);
    int r = (int)(sr >> 27);
    float ex = __expf(aout[(size_t)i*HH + h] - m);
    uint_t vv = *(const uint_t*)(vb + (size_t)s*DD + (lane<<1));
    float v0 = ex * bf2f((ushort_t)(vv & 0xffffu));
    float v1 = ex * bf2f((ushort_t)(vv >> 16));
    a00 += (r==0)?v0:0.f; a01 += (r==0)?v1:0.f;
    a10 += (r==1)?v0:0.f; a11 += (r==1)?v1:0.f;
    a20 += (r==2)?v0:0.f; a21 += (r==2)?v1:0.f;
    a30 += (r==3)?v0:0.f; a31 += (r==3)?v1:0.f;
    a40 += (r==4)?v0:0.f; a41 += (r==4)?v1:0.f;
    a50 += (r==5)?v0:0.f; a51 += (r==5)?v1:0.f;
  }
  float inv = (den > 0.f) ? 1.f/den : 0.f;
  ushort_t* sb = sacc + (size_t)n*(RR*DD);
  uint_t* sb32 = (uint_t*)sb;
  int cw = lane;   // word index within 128-dim row (64 words)
  sb32[(0<<6)+cw] = (uint_t)f2bf(a00*inv) | ((uint_t)f2bf(a01*inv) << 16);
  sb32[(1<<6)+cw] = (uint_t)f2bf(a10*inv) | ((uint_t)f2bf(a11*inv) << 16);
  sb32[(2<<6)+cw] = (uint_t)f2bf(a20*inv) | ((uint_t)f2bf(a21*inv) << 16);
  sb32[(3<<6)+cw] = (uint_t)f2bf(a30*inv) | ((uint_t)f2bf(a31*inv) << 16);
  sb32[(4<<6)+cw] = (uint_t)f2bf(a40*inv) | ((uint_t)f2bf(a41*inv) << 16);
  sb32[(5<<6)+cw] = (uint_t)f2bf(a50*inv) | ((uint_t)f2bf(a51*inv) << 16);
}

// ---------------- W_msg apply + typed Wa GEMM + skip gate + LayerNorm ----------------
__global__ __launch_bounds__(256) void ha_kernel(
    const ushort_t* __restrict__ sacc, const float* __restrict__ x, const int* __restrict__ ntype,
    const float* __restrict__ Wmsg, const float* __restrict__ Wa, const float* __restrict__ skipl,
    const float* __restrict__ lng, const float* __restrict__ lnb,
    float* __restrict__ xout)
{
  __shared__ ushort_t ss[16*RR*DD];   // 16 nodes x 768 = 24KB
  __shared__ float xs[16][DD];
  __shared__ int nts[16];
  int tid = threadIdx.x;
  int n0 = blockIdx.x * 16;
  #pragma unroll
  for (int it=0; it<12; it++){
    int c4 = tid + it*256;            // 3072 chunks of 4 ushorts
    int j = c4 / 192;
    int k = (c4 - j*192) * 4;
    *(uint2*)&ss[j*768 + k] = *(const uint2*)&sacc[(size_t)(n0+j)*768 + k];
  }
  if (tid < 16) nts[tid] = ntype[n0 + tid];
  __syncthreads();
  int c = tid & 127, nb = (tid >> 7) * 8;
  int h = c >> 5, o = c & 31;
  float agg8[8];
  #pragma unroll
  for (int j=0;j<8;j++) agg8[j]=0.f;
  #pragma unroll
  for (int r=0;r<RR;r++){
    const float* wm = Wmsg + ((h*RR + r) << 10) + o;
    const ushort_t* s0 = ss + r*DD + (h<<5);
    #pragma unroll 8
    for (int d=0; d<DHH; d++){
      float w = wm[d << 5];
      #pragma unroll
      for (int j=0;j<8;j++)
        agg8[j] += w * bf2f(s0[(nb+j)*768 + d]);
    }
  }
  #pragma unroll
  for (int j=0;j<8;j++) xs[nb+j][c] = agg8[j];
  __syncthreads();
  float acc[8];
  #pragma unroll
  for (int j=0;j<8;j++) acc[j]=0.f;
  int t0 = nts[nb];
  bool uni = true;
  #pragma unroll
  for (int j=1;j<8;j++) uni = uni && (nts[nb+j] == t0);
  if (uni){
    const float* wa = Wa + (size_t)t0*DD*DD + c;
    for (int d=0; d<DD; d+=4){
      float w0=wa[(d+0)*DD], w1=wa[(d+1)*DD], w2=wa[(d+2)*DD], w3=wa[(d+3)*DD];
      #pragma unroll
      for (int j=0;j<8;j++){
        float4 xv = *(const float4*)&xs[nb+j][d];
        acc[j] += xv.x*w0 + xv.y*w1 + xv.z*w2 + xv.w*w3;
      }
    }
  } else {
    #pragma unroll
    for (int j=0;j<8;j++){
      int t = nts[nb+j];
      const float* wa = Wa + (size_t)t*DD*DD + c;
      float sacc2 = 0.f;
      for (int d=0; d<DD; d+=4){
        float4 xv = *(const float4*)&xs[nb+j][d];
        sacc2 += xv.x*wa[d*DD] + xv.y*wa[(d+1)*DD] + xv.z*wa[(d+2)*DD] + xv.w*wa[(d+3)*DD];
      }
      acc[j] = sacc2;
    }
  }
  __syncthreads();
  #pragma unroll
  for (int j=0;j<8;j++){
    int n = n0 + nb + j;
    float sk = 1.f/(1.f + __expf(-skipl[nts[nb+j]]));
    float xv = x[(size_t)n*DD + c];
    xs[nb+j][c] = acc[j]*sk + xv*(2.f - sk);   // x + (acc*sk + x*(1-sk))
  }
  __syncthreads();
  int lane = tid & 63;
  int r0 = tid >> 6;
  #pragma unroll
  for (int rr = r0; rr < 16; rr += 4){
    float t0v = xs[rr][lane], t1v = xs[rr][lane+64];
    float s = t0v + t1v;
    #pragma unroll
    for (int off=32; off>0; off>>=1) s += __shfl_xor(s, off);
    float mu = s * (1.f/DD);
    float d0 = t0v-mu, d1 = t1v-mu;
    float vs = d0*d0 + d1*d1;
    #pragma unroll
    for (int off=32; off>0; off>>=1) vs += __shfl_xor(vs, off);
    float inv = rsqrtf(vs*(1.f/DD) + EPSF);
    size_t base = (size_t)(n0+rr)*DD;
    xout[base+lane]    = d0*inv*lng[lane]    + lnb[lane];
    xout[base+lane+64] = d1*inv*lng[lane+64] + lnb[lane+64];
  }
}

// ---------------- final mix + LayerNorm ----------------
__global__ __launch_bounds__(256) void final_kernel(
    const float* __restrict__ x1, const float* __restrict__ x2,
    const float* __restrict__ aggw, const float* __restrict__ g, const float* __restrict__ b,
    float* __restrict__ out)
{
  int lane = threadIdx.x & 63;
  int n = blockIdx.x*4 + (threadIdx.x >> 6);
  float a0 = aggw[0], a1 = aggw[1];
  float m = fmaxf(a0, a1);
  float e0 = __expf(a0-m), e1 = __expf(a1-m);
  float inv01 = 1.f/(e0+e1);
  float w0 = e0*inv01, w1 = e1*inv01;
  size_t base = (size_t)n*DD;
  float t0 = w0*x1[base+lane]    + w1*x2[base+lane];
  float t1 = w0*x1[base+lane+64] + w1*x2[base+lane+64];
  float s = t0 + t1;
  #pragma unroll
  for (int off=32; off>0; off>>=1) s += __shfl_xor(s, off);
  float mu = s * (1.f/DD);
  float d0 = t0-mu, d1 = t1-mu;
  float vs = d0*d0 + d1*d1;
  #pragma unroll
  for (int off=32; off>0; off>>=1) vs += __shfl_xor(vs, off);
  float invv = rsqrtf(vs*(1.f/DD) + EPSF);
  out[base+lane]    = d0*invv*g[lane]    + b[lane];
  out[base+lane+64] = d1*invv*g[lane+64] + b[lane+64];
}

extern "C" void kernel_launch(void* const* d_in, const int* in_sizes, int n_in,
                              void* d_out, int out_size, void* d_ws, size_t ws_size,
                              hipStream_t stream)
{
  (void)in_sizes; (void)n_in; (void)out_size; (void)ws_size;
  const float* h_in  = (const float*)d_in[0];
  const int*   src   = (const int*)d_in[1];
  const int*   dst   = (const int*)d_in[2];
  const int*   ntype = (const int*)d_in[3];
  const int*   etype = (const int*)d_in[4];
  const float* Wk    = (const float*)d_in[5];
  const float* Wq    = (const float*)d_in[6];
  const float* Wv    = (const float*)d_in[7];
  const float* Wa    = (const float*)d_in[8];
  const float* Watt  = (const float*)d_in[9];
  const float* Wmsg  = (const float*)d_in[10];
  const float* pri   = (const float*)d_in[11];
  const float* skp   = (const float*)d_in[12];
  const float* lng   = (const float*)d_in[13];
  const float* lnb   = (const float*)d_in[14];
  const float* aggw  = (const float*)d_in[15];
  const float* aggg  = (const float*)d_in[16];
  const float* aggb_ = (const float*)d_in[17];

  size_t P = (size_t)NN*DD;
  ushort_t* kb16 = (ushort_t*)d_ws;                 // P bf16
  ushort_t* vb16 = kb16 + P;                        // P bf16
  float* qbuf  = (float*)(vb16 + P);                // P f32
  ushort_t* qh = (ushort_t*)(qbuf + P);             // N*R*D bf16
  ushort_t* sacc = qh + (size_t)NN*RR*DD;           // N*R*D bf16
  float* aoutb = (float*)(sacc + (size_t)NN*RR*DD); // E*H f32
  float* out0  = aoutb + (size_t)NE*HH;             // P f32
  int* rowptr = (int*)(out0 + P);
  int* cnt    = rowptr + NN + 1;
  uint_t* srcr = (uint_t*)(cnt + NN);               // NE packed (src | etype<<27)
  int* dstp   = (int*)(srcr + NE);                  // NE dst in CSR order
  float* xout = (float*)d_out;

  // CSR by dst
  hipMemsetAsync(cnt, 0, NN*sizeof(int), stream);
  hist_kernel<<<(NE+255)/256, 256, 0, stream>>>(dst, cnt);
  scan_kernel<<<1, 1024, 0, stream>>>(cnt, rowptr);
  hipMemsetAsync(cnt, 0, NN*sizeof(int), stream);
  scatter_kernel<<<(NE+255)/256, 256, 0, stream>>>(dst, src, etype, rowptr, cnt, srcr, dstp);

  const float* x = h_in;
  for (int l=0; l<LL; l++){
    const float* Wk_l  = Wk  + (size_t)l*TT*DD*DD;
    const float* Wq_l  = Wq  + (size_t)l*TT*DD*DD;
    const float* Wv_l  = Wv  + (size_t)l*TT*DD*DD;
    const float* Wa_l  = Wa  + (size_t)l*TT*DD*DD;
    const float* Wat_l = Watt + (size_t)l*HH*RR*DHH*DHH;
    const float* Wms_l = Wmsg + (size_t)l*HH*RR*DHH*DHH;
    const float* pri_l = pri + (size_t)l*HH*RR;
    const float* skp_l = skp + (size_t)l*TT;

    kqv_kernel<<<NN/16, 256, 0, stream>>>(x, ntype, Wk_l, Wq_l, Wv_l, kb16, qbuf, vb16);
    qhat_kernel<<<NN/16, 256, 0, stream>>>(qbuf, Wat_l, qh);
    logit_kernel<<<(NE*HH+255)/256, 256, 0, stream>>>(kb16, qh, srcr, dstp, pri_l, aoutb);
    reduce_kernel<<<(NN+3)/4, 256, 0, stream>>>(vb16, aoutb, rowptr, srcr, sacc);
    float* xo = (l == 0) ? out0 : xout;
    ha_kernel<<<NN/16, 256, 0, stream>>>(sacc, x, ntype, Wms_l, Wa_l, skp_l,
                                         lng + (size_t)l*DD, lnb + (size_t)l*DD, xo);
    x = xo;
  }
  final_kernel<<<NN/4, 256, 0, stream>>>(out0, xout, aggw, aggg, aggb_, xout);
}